// Round 15
// baseline (289.526 us; speedup 1.0000x reference)
//
#include <hip/hip_runtime.h>
#include <hip/hip_bf16.h>

// q = rownorm( 1 / (1 + ||x - c||^2) ), ALPHA=1
// x: (262144, 256) f32 ; clusters: (256, 256) f32 ; out: (262144, 256) f32
//
// R15: dual-strip ILP. Occupancy is walled at 2 waves/SIMD (block size sets
// the waves/SIMD floor; capped configs split regs 50/50 arch/AGPR — R11/R13/
// R14 evidence), so raise per-wave memory-level parallelism instead: each
// col-split wave pair processes TWO 16-row strips concurrently. Second
// accumulator lives in the otherwise-WASTED AGPR half (acc 2x32=64 <= 128).
// The two strips share every B ds_read (one bfrag -> mfmaA+mfmaB): LDS reads
// and pair handshakes halve. Two 32-reg xv buffers stay perpetually in
// flight -> ~2x avg outstanding HBM bytes per wave (the measured limiter:
// R10's BW matched ~20% load-in-flight duty). csq moved to LDS (-8 arch).

#define NROWS 262144
#define DDIM  256
#define KCL   256
#define GRID  256
#define PPB   4                        // pairs per block (8 waves)
#define NPAIRS (GRID * PPB)            // 1024
#define NSUPER 8                       // superstrips per pair (2 strips each)
// strips: sA = g + 2*NPAIRS*j, sB = sA + NPAIRS ; 1024*2*8 = 16384 = NROWS/16

using f32x4  = __attribute__((ext_vector_type(4))) float;
using s16x8  = __attribute__((ext_vector_type(8))) short;

__device__ inline unsigned short f2bf(float f) {
    unsigned int u = __float_as_uint(f);
    u += 0x7fffu + ((u >> 16) & 1u);
    return (unsigned short)(u >> 16);
}

__device__ inline short bfc(float f) {
    return (short)__bfloat16_as_ushort(__float2bfloat16(f));
}

// One wave per cluster row: convert to bf16, compute ||c||^2.
__global__ void prep_kernel(const float* __restrict__ clusters,
                            unsigned short* __restrict__ cb,
                            float* __restrict__ csq) {
    int k    = blockIdx.x;
    int lane = threadIdx.x;  // 64 threads
    const float* row = clusters + (size_t)k * DDIM;
    float4 a = *reinterpret_cast<const float4*>(row + lane * 4);
    ushort4 b;
    b.x = f2bf(a.x); b.y = f2bf(a.y); b.z = f2bf(a.z); b.w = f2bf(a.w);
    *reinterpret_cast<ushort4*>(cb + (size_t)k * DDIM + lane * 4) = b;
    float ss = a.x*a.x + a.y*a.y + a.z*a.z + a.w*a.w;
    #pragma unroll
    for (int m = 1; m < 64; m <<= 1) ss += __shfl_xor(ss, m);
    if (lane == 0) csq[k] = ss;
}

// 8 waves/block: wave w -> rg = w>>1 (pair 0..3), ch = w&1 (col half).
// Pair g handles strips sA = g+2048j and sB = sA+1024 TOGETHER.
// A-frag: lane holds x[row + (l&15)][s*32 + (l>>4)*8 + jj], jj=0..7
// B-frag: lane holds c[ch*128 + f*16 + (l&15)][s*32 + (l>>4)*8 + jj]
// C/D   : col = l&15, row = (l>>4)*4 + reg   [verified layout, m89]
__global__ __launch_bounds__(512, 2) void fused_kernel(
    const float* __restrict__ x,
    const unsigned short* __restrict__ cb,
    const float* __restrict__ csq,
    float* __restrict__ out) {

    __shared__ char  lds_b[KCL * DDIM * 2];   // 128 KB: full B, swizzled
    __shared__ float ls_csq[KCL];             // 1 KB: ||c||^2
    __shared__ float ls_sum[2][2][2][PPB][16];// [j&1][A/B][ch][rg][row]
    __shared__ int   ls_flag[2][PPB];         // [ch][rg] superstrips done

    const int tid  = threadIdx.x;
    const int lane = tid & 63;
    const int wave = tid >> 6;               // 0..7
    const int rg   = wave >> 1;              // 0..3
    const int ch   = wave & 1;               // 0..1
    const int c15  = lane & 15;
    const int kch  = lane >> 4;              // 0..3

    const int g = blockIdx.x * PPB + rg;     // pair id 0..1023

    // ---- stage full B into LDS (linear dest, swizzled global source) ----
    #pragma unroll
    for (int it = 0; it < 16; ++it) {
        int slot = it * 8192 + tid * 16;
        int src  = slot ^ (((slot >> 9) & 7) << 4);
        __builtin_amdgcn_global_load_lds(
            (const __attribute__((address_space(1))) unsigned int*)((const char*)cb + src),
            (__attribute__((address_space(3))) unsigned int*)(lds_b + slot),
            16, 0, 0);
    }
    if (tid < KCL) ls_csq[tid] = csq[tid];
    if (tid < 2 * PPB) ((int*)ls_flag)[tid] = 0;

    // per-lane x base for strip id s
    auto xbase = [&](int sid) -> const float* {
        return x + (size_t)(sid * 16 + c15) * DDIM + kch * 8;
    };
    auto loadhalf = [&](f32x4* xv, const float* base) {
        #pragma unroll
        for (int i = 0; i < 8; ++i)
            xv[i] = *reinterpret_cast<const f32x4*>(base + (i >> 1) * 32 + (i & 1) * 4);
    };

    f32x4 xvA[8], xvB[8];
    // ---- prologue: both strips' first halves fly under B staging ----
    loadhalf(xvA, xbase(g));
    loadhalf(xvB, xbase(g + NPAIRS));

    __syncthreads();   // drains vmcnt; B + csq + flags ready (only barrier)

    // convert one half: xv -> af[0..3], accumulate squares into q0,q1
    auto convhalf = [&](const f32x4* xv, s16x8* af, float& q0, float& q1) {
        #pragma unroll
        for (int s4 = 0; s4 < 4; ++s4) {
            f32x4 xa = xv[2 * s4], xb = xv[2 * s4 + 1];
            float t0 = xa[0]*xa[0] + xa[1]*xa[1];
            float t1 = xa[2]*xa[2] + xa[3]*xa[3];
            float t2 = xb[0]*xb[0] + xb[1]*xb[1];
            float t3 = xb[2]*xb[2] + xb[3]*xb[3];
            if (s4 & 1) q1 += (t0 + t1) + (t2 + t3);
            else        q0 += (t0 + t1) + (t2 + t3);
            af[s4][0] = bfc(xa[0]); af[s4][1] = bfc(xa[1]);
            af[s4][2] = bfc(xa[2]); af[s4][3] = bfc(xa[3]);
            af[s4][4] = bfc(xb[0]); af[s4][5] = bfc(xb[1]);
            af[s4][6] = bfc(xb[2]); af[s4][7] = bfc(xb[3]);
        }
    };

    #pragma unroll 1
    for (int j = 0; j < NSUPER; ++j) {
        const int sA = g + 2 * NPAIRS * j;
        const int sB = sA + NPAIRS;
        const float* xrA = xbase(sA);
        const float* xrB = xbase(sB);

        s16x8 afA[4], afB[4];
        float pA0 = 0.f, pA1 = 0.f, pB0 = 0.f, pB1 = 0.f;

        // ---- halves 1: convert, then refill xv with halves 2 ----
        convhalf(xvA, afA, pA0, pA1);
        loadhalf(xvA, xrA + 128);
        convhalf(xvB, afB, pB0, pB1);
        loadhalf(xvB, xrB + 128);

        f32x4 accA[8], accB[8];
        #pragma unroll
        for (int f = 0; f < 8; ++f) {
            accA[f] = (f32x4){0.f, 0.f, 0.f, 0.f};
            accB[f] = (f32x4){0.f, 0.f, 0.f, 0.f};
        }

        // ---- MFMA s0-3: one bfrag read feeds BOTH strips ----
        #pragma unroll
        for (int s = 0; s < 4; ++s) {
            #pragma unroll
            for (int f = 0; f < 8; ++f) {
                int ba = ((ch * 128 + f * 16 + c15) * 512) + s * 64 + kch * 16;
                ba ^= ((c15 & 7) << 4);
                s16x8 bfrag = *reinterpret_cast<const s16x8*>(lds_b + ba);
                accA[f] = __builtin_amdgcn_mfma_f32_16x16x32_bf16(afA[s], bfrag,
                                                                  accA[f], 0, 0, 0);
                accB[f] = __builtin_amdgcn_mfma_f32_16x16x32_bf16(afB[s], bfrag,
                                                                  accB[f], 0, 0, 0);
            }
        }

        // ---- halves 2: convert, then refill xv with next superstrip ----
        convhalf(xvA, afA, pA0, pA1);
        if (j + 1 < NSUPER) loadhalf(xvA, xbase(sA + 2 * NPAIRS));
        convhalf(xvB, afB, pB0, pB1);
        if (j + 1 < NSUPER) loadhalf(xvB, xbase(sB + 2 * NPAIRS));

        // ---- MFMA s4-7 ----
        #pragma unroll
        for (int s = 0; s < 4; ++s) {
            #pragma unroll
            for (int f = 0; f < 8; ++f) {
                int ba = ((ch * 128 + f * 16 + c15) * 512) + (s + 4) * 64 + kch * 16;
                ba ^= ((c15 & 7) << 4);
                s16x8 bfrag = *reinterpret_cast<const s16x8*>(lds_b + ba);
                accA[f] = __builtin_amdgcn_mfma_f32_16x16x32_bf16(afA[s], bfrag,
                                                                  accA[f], 0, 0, 0);
                accB[f] = __builtin_amdgcn_mfma_f32_16x16x32_bf16(afB[s], bfrag,
                                                                  accB[f], 0, 0, 0);
            }
        }

        // ---- epilogue: student-t + partial row sums, both strips ----
        float psA[4], psB[4];
        auto epi = [&](f32x4* acc, float p0, float p1, float* ps, int ab) {
            float xsq = p0 + p1;
            xsq += __shfl_xor(xsq, 16);
            xsq += __shfl_xor(xsq, 32);
            #pragma unroll
            for (int r = 0; r < 4; ++r) {
                float xrr = __shfl(xsq, kch * 4 + r);
                float s = 0.f;
                #pragma unroll
                for (int f = 0; f < 8; ++f) {
                    float d2 = xrr - 2.0f * acc[f][r] + ls_csq[ch * 128 + f * 16 + c15];
                    float qv = __builtin_amdgcn_rcpf(1.0f + d2);  // ALPHA=1
                    acc[f][r] = qv;
                    s += qv;
                }
                s += __shfl_xor(s, 1);
                s += __shfl_xor(s, 2);
                s += __shfl_xor(s, 4);
                s += __shfl_xor(s, 8);
                ps[r] = s;
                if (c15 == 0) ls_sum[j & 1][ab][ch][rg][kch * 4 + r] = s;
            }
        };
        epi(accA, pA0, pA1, psA, 0);
        epi(accB, pB0, pB1, psB, 1);

        // ---- ONE pairwise handshake for both strips ----
        asm volatile("s_waitcnt lgkmcnt(0)" ::: "memory");
        if (lane == 0)
            __atomic_store_n(&ls_flag[ch][rg], j + 1, __ATOMIC_RELAXED);
        volatile int* pf = (volatile int*)&ls_flag[ch ^ 1][rg];
        while (*pf <= j) { }
        asm volatile("" ::: "memory");

        // ---- normalize + NT stores, both strips ----
        auto dostores = [&](f32x4* acc, const float* ps, int ab, int sid) {
            #pragma unroll
            for (int r = 0; r < 4; ++r) {
                float other = ls_sum[j & 1][ab][ch ^ 1][rg][kch * 4 + r];
                float inv = __builtin_amdgcn_rcpf(ps[r] + other);
                const size_t orow = (size_t)(sid * 16 + kch * 4 + r) * KCL;
                #pragma unroll
                for (int f = 0; f < 8; ++f) {
                    __builtin_nontemporal_store(acc[f][r] * inv,
                                                &out[orow + ch * 128 + f * 16 + c15]);
                }
            }
        };
        dostores(accA, psA, 0, sA);
        dostores(accB, psB, 1, sB);
    }
}

extern "C" void kernel_launch(void* const* d_in, const int* in_sizes, int n_in,
                              void* d_out, int out_size, void* d_ws, size_t ws_size,
                              hipStream_t stream) {
    const float* x        = (const float*)d_in[0];
    const float* clusters = (const float*)d_in[1];
    float* out = (float*)d_out;

    // ws layout: [0, 128KB) clusters as bf16 ; [128KB, +1KB) c_sq f32
    unsigned short* cb  = (unsigned short*)d_ws;
    float*          csq = (float*)((char*)d_ws + (size_t)KCL * DDIM * sizeof(unsigned short));

    prep_kernel<<<KCL, 64, 0, stream>>>(clusters, cb, csq);
    fused_kernel<<<GRID, 512, 0, stream>>>(x, cb, csq, out);
}

// Round 16
// 197.381 us; speedup vs baseline: 1.4668x; 1.4668x over previous
//
#include <hip/hip_runtime.h>

// q = rownorm( 1 / (1 + ||x - c||^2) ), ALPHA=1
// x: (262144, 256) f32 ; clusters: (256, 256) f32 ; out: (262144, 256) f32
//
// R16: R10 (131us champion: col-split wave pairs, pairwise LDS-flag sync,
// rcpf epilogue, 124 arch regs no-spill) + B-fragment hoisting. B is
// strip-invariant, yet R10 re-read 64 ds_read_b128 per wave-strip. The AGPR
// half of the unified file is 128 regs and acc only uses 32 -> 96 free.
// Hoist k-steps s=0..2's B-frags (24 frags = 96 regs) out of the strip loop:
// loop-invariant values under arch pressure go to AGPRs (v->a spill), and
// gfx950 MFMA sources B directly from AGPRs (ISA §10). ds_reads 64->40 per
// strip; MFMA s0-2 have no LDS dependency. xv2 issue moved to strip top so
// convert1 + 24 reg-only MFMAs cover its full HBM latency.

#define NROWS 262144
#define DDIM  256
#define KCL   256
#define TPB   16                      // 64-row tiles per block
#define GRID  (NROWS / 64 / TPB)      // 256 blocks = 1 per CU

using f32x4  = __attribute__((ext_vector_type(4))) float;
using s16x8  = __attribute__((ext_vector_type(8))) short;

__device__ inline unsigned short f2bf(float f) {
    // round-to-nearest-even f32 -> bf16
    unsigned int u = __float_as_uint(f);
    u += 0x7fffu + ((u >> 16) & 1u);
    return (unsigned short)(u >> 16);
}

// One wave per cluster row: convert to bf16, compute ||c||^2.
__global__ void prep_kernel(const float* __restrict__ clusters,
                            unsigned short* __restrict__ cb,
                            float* __restrict__ csq) {
    int k    = blockIdx.x;
    int lane = threadIdx.x;  // 64 threads
    const float* row = clusters + (size_t)k * DDIM;
    float4 a = *reinterpret_cast<const float4*>(row + lane * 4);
    ushort4 b;
    b.x = f2bf(a.x); b.y = f2bf(a.y); b.z = f2bf(a.z); b.w = f2bf(a.w);
    *reinterpret_cast<ushort4*>(cb + (size_t)k * DDIM + lane * 4) = b;
    float ss = a.x*a.x + a.y*a.y + a.z*a.z + a.w*a.w;
    #pragma unroll
    for (int m = 1; m < 64; m <<= 1) ss += __shfl_xor(ss, m);
    if (lane == 0) csq[k] = ss;
}

// 8 waves/block: wave w -> rg = w>>1 (pair), ch = w&1 (col half).
// Wave computes rows [trow+rg*16, +16) x cols [ch*128, +128).
// A-frag: lane holds x[row + (l&15)][s*32 + (l>>4)*8 + j], j=0..7
// B-frag: lane holds c[ch*128 + f*16 + (l&15)][s*32 + (l>>4)*8 + j], f=0..7
// C/D   : col = l&15, row = (l>>4)*4 + reg   [verified layout, m89]
__global__ __launch_bounds__(512, 2) void fused_kernel(
    const float* __restrict__ x,
    const unsigned short* __restrict__ cb,
    const float* __restrict__ csq,
    float* __restrict__ out) {

    __shared__ char  lds_b[KCL * DDIM * 2];   // 128 KB: full B, swizzled
    __shared__ float ls_sum[TPB][2][4][16];   // per-tile slots: no reuse hazard
    __shared__ int   ls_flag[2][4];           // [ch][rg] tiles-completed counter

    const int tid  = threadIdx.x;
    const int lane = tid & 63;
    const int wave = tid >> 6;               // 0..7
    const int rg   = wave >> 1;              // 0..3
    const int ch   = wave & 1;               // 0..1
    const int c15  = lane & 15;
    const int kch  = lane >> 4;              // 0..3

    const int tile0 = blockIdx.x * TPB;

    // ---- stage full B into LDS (linear dest, swizzled global source) ----
    #pragma unroll
    for (int it = 0; it < 16; ++it) {
        int slot = it * 8192 + tid * 16;
        int src  = slot ^ (((slot >> 9) & 7) << 4);
        __builtin_amdgcn_global_load_lds(
            (const __attribute__((address_space(1))) unsigned int*)((const char*)cb + src),
            (__attribute__((address_space(3))) unsigned int*)(lds_b + slot),
            16, 0, 0);
    }

    if (tid < 8) ((int*)ls_flag)[tid] = 0;

    // csq fragment for this wave's col half (8 regs)
    float cs[8];
    #pragma unroll
    for (int f = 0; f < 8; ++f) cs[f] = csq[ch * 128 + f * 16 + c15];

    __syncthreads();   // drains vmcnt; B + flags ready (only block barrier)

    // LDS byte address of B-frag (f, s) for this lane (read-side swizzle)
    auto baddr = [&](int f, int s) -> int {
        int ba = ((ch * 128 + f * 16 + c15) * 512) + s * 64 + kch * 16;
        return ba ^ ((c15 & 7) << 4);
    };

    // ---- hoist k-steps s=0..2's B-frags: loop-invariant, 96 regs ->
    //      lands in the otherwise-idle AGPR half (acc uses only 32/128) ----
    s16x8 bs0[8], bs1[8], bs2[8];
    #pragma unroll
    for (int f = 0; f < 8; ++f) {
        bs0[f] = *reinterpret_cast<const s16x8*>(lds_b + baddr(f, 0));
        bs1[f] = *reinterpret_cast<const s16x8*>(lds_b + baddr(f, 1));
        bs2[f] = *reinterpret_cast<const s16x8*>(lds_b + baddr(f, 2));
    }

    // per-lane x base for tile t
    auto xrow = [&](int t) -> const float* {
        return x + (size_t)((tile0 + t) * 64 + rg * 16 + c15) * DDIM + kch * 8;
    };

    f32x4 xv1[8], xv2[8];

    // ---- prologue: issue tile 0's first k-half ----
    {
        const float* xr = xrow(0);
        #pragma unroll
        for (int i = 0; i < 8; ++i)
            xv1[i] = *reinterpret_cast<const f32x4*>(xr + (i >> 1) * 32 + (i & 1) * 4);
    }

    #pragma unroll 1
    for (int t = 0; t < TPB; ++t) {
        const int trow = (tile0 + t) * 64;
        const float* xr = xrow(t);

        // ---- issue batch 2 (k 128..255) FIRST: convert1 + 24 reg-only
        //      MFMAs cover its full HBM latency ----
        #pragma unroll
        for (int i = 0; i < 8; ++i) {
            int ii = 8 + i;
            xv2[i] = *reinterpret_cast<const f32x4*>(xr + (ii >> 1) * 32 + (ii & 1) * 4);
        }

        s16x8 afrag[8];
        float p[4] = {0.f, 0.f, 0.f, 0.f};

        // ---- convert batch 1 (k 0..127) -> afrag[0..3] ----
        #pragma unroll
        for (int s4 = 0; s4 < 4; ++s4) {
            f32x4 xa = xv1[2 * s4], xb = xv1[2 * s4 + 1];
            float t0 = xa[0]*xa[0] + xa[1]*xa[1];
            float t1 = xa[2]*xa[2] + xa[3]*xa[3];
            float t2 = xb[0]*xb[0] + xb[1]*xb[1];
            float t3 = xb[2]*xb[2] + xb[3]*xb[3];
            p[s4] += (t0 + t1) + (t2 + t3);
            afrag[s4][0] = (short)f2bf(xa[0]); afrag[s4][1] = (short)f2bf(xa[1]);
            afrag[s4][2] = (short)f2bf(xa[2]); afrag[s4][3] = (short)f2bf(xa[3]);
            afrag[s4][4] = (short)f2bf(xb[0]); afrag[s4][5] = (short)f2bf(xb[1]);
            afrag[s4][6] = (short)f2bf(xb[2]); afrag[s4][7] = (short)f2bf(xb[3]);
        }

        f32x4 acc[8];
        #pragma unroll
        for (int f = 0; f < 8; ++f) acc[f] = (f32x4){0.f, 0.f, 0.f, 0.f};

        // ---- MFMA s=0..2 from hoisted regs (no LDS dependency) ----
        #pragma unroll
        for (int f = 0; f < 8; ++f)
            acc[f] = __builtin_amdgcn_mfma_f32_16x16x32_bf16(afrag[0], bs0[f],
                                                             acc[f], 0, 0, 0);
        #pragma unroll
        for (int f = 0; f < 8; ++f)
            acc[f] = __builtin_amdgcn_mfma_f32_16x16x32_bf16(afrag[1], bs1[f],
                                                             acc[f], 0, 0, 0);
        #pragma unroll
        for (int f = 0; f < 8; ++f)
            acc[f] = __builtin_amdgcn_mfma_f32_16x16x32_bf16(afrag[2], bs2[f],
                                                             acc[f], 0, 0, 0);
        // ---- MFMA s=3 from LDS ----
        #pragma unroll
        for (int f = 0; f < 8; ++f) {
            s16x8 bfrag = *reinterpret_cast<const s16x8*>(lds_b + baddr(f, 3));
            acc[f] = __builtin_amdgcn_mfma_f32_16x16x32_bf16(afrag[3], bfrag,
                                                             acc[f], 0, 0, 0);
        }

        // ---- convert batch 2 (k 128..255) -> afrag[4..7] ----
        #pragma unroll
        for (int s4 = 0; s4 < 4; ++s4) {
            f32x4 xa = xv2[2 * s4], xb = xv2[2 * s4 + 1];
            float t0 = xa[0]*xa[0] + xa[1]*xa[1];
            float t1 = xa[2]*xa[2] + xa[3]*xa[3];
            float t2 = xb[0]*xb[0] + xb[1]*xb[1];
            float t3 = xb[2]*xb[2] + xb[3]*xb[3];
            p[s4] += (t0 + t1) + (t2 + t3);
            int s = 4 + s4;
            afrag[s][0] = (short)f2bf(xa[0]); afrag[s][1] = (short)f2bf(xa[1]);
            afrag[s][2] = (short)f2bf(xa[2]); afrag[s][3] = (short)f2bf(xa[3]);
            afrag[s][4] = (short)f2bf(xb[0]); afrag[s][5] = (short)f2bf(xb[1]);
            afrag[s][6] = (short)f2bf(xb[2]); afrag[s][7] = (short)f2bf(xb[3]);
        }

        // ---- prefetch next tile's batch 1: flies through epilogue+sync ----
        if (t + 1 < TPB) {
            const float* xn = xrow(t + 1);
            #pragma unroll
            for (int i = 0; i < 8; ++i)
                xv1[i] = *reinterpret_cast<const f32x4*>(xn + (i >> 1) * 32 + (i & 1) * 4);
        }

        // ---- MFMA s=4..7 from LDS ----
        #pragma unroll
        for (int s = 4; s < 8; ++s) {
            #pragma unroll
            for (int f = 0; f < 8; ++f) {
                s16x8 bfrag = *reinterpret_cast<const s16x8*>(lds_b + baddr(f, s));
                acc[f] = __builtin_amdgcn_mfma_f32_16x16x32_bf16(afrag[s], bfrag,
                                                                 acc[f], 0, 0, 0);
            }
        }

        // ---- epilogue: student-t + 128-col partial row sums ----
        float xsq = (p[0] + p[1]) + (p[2] + p[3]);
        xsq += __shfl_xor(xsq, 16);
        xsq += __shfl_xor(xsq, 32);
        // lane l now holds xsq of row trow + rg*16 + (l&15)

        float psum[4];
        #pragma unroll
        for (int r = 0; r < 4; ++r) {
            float xrr = __shfl(xsq, kch * 4 + r);
            float s = 0.f;
            #pragma unroll
            for (int f = 0; f < 8; ++f) {
                float d2 = xrr - 2.0f * acc[f][r] + cs[f];
                float qv = __builtin_amdgcn_rcpf(1.0f + d2);  // ALPHA=1 -> exp==1
                acc[f][r] = qv;
                s += qv;
            }
            s += __shfl_xor(s, 1);
            s += __shfl_xor(s, 2);
            s += __shfl_xor(s, 4);
            s += __shfl_xor(s, 8);
            psum[r] = s;   // sum over this wave's 128 cols, row kch*4+r
        }

        // ---- pairwise handshake (no block barrier, no vmcnt drain) ----
        if (c15 == 0) {
            #pragma unroll
            for (int r = 0; r < 4; ++r)
                ls_sum[t][ch][rg][kch * 4 + r] = psum[r];
        }
        asm volatile("s_waitcnt lgkmcnt(0)" ::: "memory");  // sums visible
        if (lane == 0)
            __atomic_store_n(&ls_flag[ch][rg], t + 1, __ATOMIC_RELAXED);

        volatile int* pf = (volatile int*)&ls_flag[ch ^ 1][rg];
        while (*pf <= t) { }
        asm volatile("" ::: "memory");   // no hoisting of sum reads above spin

        const int row0t = trow + rg * 16;
        #pragma unroll
        for (int r = 0; r < 4; ++r) {
            float other = ls_sum[t][ch ^ 1][rg][kch * 4 + r];
            float inv = __builtin_amdgcn_rcpf(psum[r] + other);
            const size_t orow = (size_t)(row0t + kch * 4 + r) * KCL;
            #pragma unroll
            for (int f = 0; f < 8; ++f) {
                __builtin_nontemporal_store(acc[f][r] * inv,
                                            &out[orow + ch * 128 + f * 16 + c15]);
            }
        }
    }
}

extern "C" void kernel_launch(void* const* d_in, const int* in_sizes, int n_in,
                              void* d_out, int out_size, void* d_ws, size_t ws_size,
                              hipStream_t stream) {
    const float* x        = (const float*)d_in[0];
    const float* clusters = (const float*)d_in[1];
    float* out = (float*)d_out;

    // ws layout: [0, 128KB) clusters as bf16 ; [128KB, +1KB) c_sq f32
    unsigned short* cb  = (unsigned short*)d_ws;
    float*          csq = (float*)((char*)d_ws + (size_t)KCL * DDIM * sizeof(unsigned short));

    prep_kernel<<<KCL, 64, 0, stream>>>(clusters, cb, csq);
    fused_kernel<<<GRID, 512, 0, stream>>>(x, cb, csq, out);
}

// Round 17
// 126.575 us; speedup vs baseline: 2.2874x; 1.5594x over previous
//
#include <hip/hip_runtime.h>

// q = rownorm( 1 / (1 + ||x - c||^2) ), ALPHA=1
// x: (262144, 256) f32 ; clusters: (256, 256) f32 ; out: (262144, 256) f32
//
// R17: R10 (131us champion) + three liveness-neutral micro-opts.
// Ledger: all structural escapes from R10's 124-reg envelope spilled
// (R9/R11-R16 — compiler allocates NO AGPRs here; everything fits one
// 128-arch cap at 2 waves/SIMD). So: consolidate within the envelope.
//  (1) xv2 issued at strip TOP (+~400cy cover for its HBM latency;
//      R16 showed this edit is liveness-safe — its spill was the B-hoist).
//  (2) s_setprio(1) around MFMA clusters (free-running waves = T5's
//      role-diversity regime, +4-7% in m191; NOT the m190 lockstep null).
//  (3) s_sleep(1) in the handshake spin (stop burning issue slots).

#define NROWS 262144
#define DDIM  256
#define KCL   256
#define TPB   16                      // 64-row tiles per block
#define GRID  (NROWS / 64 / TPB)      // 256 blocks = 1 per CU

using f32x4  = __attribute__((ext_vector_type(4))) float;
using s16x8  = __attribute__((ext_vector_type(8))) short;

__device__ inline unsigned short f2bf(float f) {
    // round-to-nearest-even f32 -> bf16
    unsigned int u = __float_as_uint(f);
    u += 0x7fffu + ((u >> 16) & 1u);
    return (unsigned short)(u >> 16);
}

// One wave per cluster row: convert to bf16, compute ||c||^2.
__global__ void prep_kernel(const float* __restrict__ clusters,
                            unsigned short* __restrict__ cb,
                            float* __restrict__ csq) {
    int k    = blockIdx.x;
    int lane = threadIdx.x;  // 64 threads
    const float* row = clusters + (size_t)k * DDIM;
    float4 a = *reinterpret_cast<const float4*>(row + lane * 4);
    ushort4 b;
    b.x = f2bf(a.x); b.y = f2bf(a.y); b.z = f2bf(a.z); b.w = f2bf(a.w);
    *reinterpret_cast<ushort4*>(cb + (size_t)k * DDIM + lane * 4) = b;
    float ss = a.x*a.x + a.y*a.y + a.z*a.z + a.w*a.w;
    #pragma unroll
    for (int m = 1; m < 64; m <<= 1) ss += __shfl_xor(ss, m);
    if (lane == 0) csq[k] = ss;
}

// 8 waves/block: wave w -> rg = w>>1 (pair), ch = w&1 (col half).
// Wave computes rows [trow+rg*16, +16) x cols [ch*128, +128).
// A-frag: lane holds x[row + (l&15)][s*32 + (l>>4)*8 + j], j=0..7
// B-frag: lane holds c[ch*128 + f*16 + (l&15)][s*32 + (l>>4)*8 + j], f=0..7
// C/D   : col = l&15, row = (l>>4)*4 + reg   [verified layout, m89]
__global__ __launch_bounds__(512, 2) void fused_kernel(
    const float* __restrict__ x,
    const unsigned short* __restrict__ cb,
    const float* __restrict__ csq,
    float* __restrict__ out) {

    __shared__ char  lds_b[KCL * DDIM * 2];   // 128 KB: full B, swizzled
    __shared__ float ls_sum[TPB][2][4][16];   // per-tile slots: no reuse hazard
    __shared__ int   ls_flag[2][4];           // [ch][rg] tiles-completed counter

    const int tid  = threadIdx.x;
    const int lane = tid & 63;
    const int wave = tid >> 6;               // 0..7
    const int rg   = wave >> 1;              // 0..3
    const int ch   = wave & 1;               // 0..1
    const int c15  = lane & 15;
    const int kch  = lane >> 4;              // 0..3

    const int tile0 = blockIdx.x * TPB;

    // ---- stage full B into LDS (linear dest, swizzled global source) ----
    #pragma unroll
    for (int it = 0; it < 16; ++it) {
        int slot = it * 8192 + tid * 16;
        int src  = slot ^ (((slot >> 9) & 7) << 4);
        __builtin_amdgcn_global_load_lds(
            (const __attribute__((address_space(1))) unsigned int*)((const char*)cb + src),
            (__attribute__((address_space(3))) unsigned int*)(lds_b + slot),
            16, 0, 0);
    }

    if (tid < 8) ((int*)ls_flag)[tid] = 0;

    // csq fragment for this wave's col half (8 regs)
    float cs[8];
    #pragma unroll
    for (int f = 0; f < 8; ++f) cs[f] = csq[ch * 128 + f * 16 + c15];

    __syncthreads();   // drains vmcnt; B + flags ready (only block barrier)

    // per-lane x base for tile t
    auto xrow = [&](int t) -> const float* {
        return x + (size_t)((tile0 + t) * 64 + rg * 16 + c15) * DDIM + kch * 8;
    };

    f32x4 xv1[8], xv2[8];

    // ---- prologue: issue tile 0's first k-half ----
    {
        const float* xr = xrow(0);
        #pragma unroll
        for (int i = 0; i < 8; ++i)
            xv1[i] = *reinterpret_cast<const f32x4*>(xr + (i >> 1) * 32 + (i & 1) * 4);
    }

    #pragma unroll 1
    for (int t = 0; t < TPB; ++t) {
        const int trow = (tile0 + t) * 64;
        const float* xr = xrow(t);

        // ---- issue batch 2 (k 128..255) at strip TOP: convert-1 + MFMA
        //      s0-3 cover its full HBM latency ----
        #pragma unroll
        for (int i = 0; i < 8; ++i) {
            int ii = 8 + i;
            xv2[i] = *reinterpret_cast<const f32x4*>(xr + (ii >> 1) * 32 + (ii & 1) * 4);
        }

        s16x8 afrag[8];
        float p[4] = {0.f, 0.f, 0.f, 0.f};

        // ---- convert batch 1 (k 0..127) -> afrag[0..3] ----
        #pragma unroll
        for (int s4 = 0; s4 < 4; ++s4) {
            f32x4 xa = xv1[2 * s4], xb = xv1[2 * s4 + 1];
            float t0 = xa[0]*xa[0] + xa[1]*xa[1];
            float t1 = xa[2]*xa[2] + xa[3]*xa[3];
            float t2 = xb[0]*xb[0] + xb[1]*xb[1];
            float t3 = xb[2]*xb[2] + xb[3]*xb[3];
            p[s4] += (t0 + t1) + (t2 + t3);
            afrag[s4][0] = (short)f2bf(xa[0]); afrag[s4][1] = (short)f2bf(xa[1]);
            afrag[s4][2] = (short)f2bf(xa[2]); afrag[s4][3] = (short)f2bf(xa[3]);
            afrag[s4][4] = (short)f2bf(xb[0]); afrag[s4][5] = (short)f2bf(xb[1]);
            afrag[s4][6] = (short)f2bf(xb[2]); afrag[s4][7] = (short)f2bf(xb[3]);
        }

        f32x4 acc[8];
        #pragma unroll
        for (int f = 0; f < 8; ++f) acc[f] = (f32x4){0.f, 0.f, 0.f, 0.f};

        __builtin_amdgcn_s_setprio(1);
        #pragma unroll
        for (int s = 0; s < 4; ++s) {
            #pragma unroll
            for (int f = 0; f < 8; ++f) {
                int ba = ((ch * 128 + f * 16 + c15) * 512) + s * 64 + kch * 16;
                ba ^= ((c15 & 7) << 4);
                s16x8 bfrag = *reinterpret_cast<const s16x8*>(lds_b + ba);
                acc[f] = __builtin_amdgcn_mfma_f32_16x16x32_bf16(afrag[s], bfrag,
                                                                 acc[f], 0, 0, 0);
            }
        }
        __builtin_amdgcn_s_setprio(0);

        // ---- convert batch 2 (k 128..255) -> afrag[4..7] ----
        #pragma unroll
        for (int s4 = 0; s4 < 4; ++s4) {
            f32x4 xa = xv2[2 * s4], xb = xv2[2 * s4 + 1];
            float t0 = xa[0]*xa[0] + xa[1]*xa[1];
            float t1 = xa[2]*xa[2] + xa[3]*xa[3];
            float t2 = xb[0]*xb[0] + xb[1]*xb[1];
            float t3 = xb[2]*xb[2] + xb[3]*xb[3];
            p[s4] += (t0 + t1) + (t2 + t3);
            int s = 4 + s4;
            afrag[s][0] = (short)f2bf(xa[0]); afrag[s][1] = (short)f2bf(xa[1]);
            afrag[s][2] = (short)f2bf(xa[2]); afrag[s][3] = (short)f2bf(xa[3]);
            afrag[s][4] = (short)f2bf(xb[0]); afrag[s][5] = (short)f2bf(xb[1]);
            afrag[s][6] = (short)f2bf(xb[2]); afrag[s][7] = (short)f2bf(xb[3]);
        }

        // ---- prefetch next tile's batch 1: flies through epilogue+sync ----
        if (t + 1 < TPB) {
            const float* xn = xrow(t + 1);
            #pragma unroll
            for (int i = 0; i < 8; ++i)
                xv1[i] = *reinterpret_cast<const f32x4*>(xn + (i >> 1) * 32 + (i & 1) * 4);
        }

        __builtin_amdgcn_s_setprio(1);
        #pragma unroll
        for (int s = 4; s < 8; ++s) {
            #pragma unroll
            for (int f = 0; f < 8; ++f) {
                int ba = ((ch * 128 + f * 16 + c15) * 512) + s * 64 + kch * 16;
                ba ^= ((c15 & 7) << 4);
                s16x8 bfrag = *reinterpret_cast<const s16x8*>(lds_b + ba);
                acc[f] = __builtin_amdgcn_mfma_f32_16x16x32_bf16(afrag[s], bfrag,
                                                                 acc[f], 0, 0, 0);
            }
        }
        __builtin_amdgcn_s_setprio(0);

        // ---- epilogue: student-t + 128-col partial row sums ----
        float xsq = (p[0] + p[1]) + (p[2] + p[3]);
        xsq += __shfl_xor(xsq, 16);
        xsq += __shfl_xor(xsq, 32);
        // lane l now holds xsq of row trow + rg*16 + (l&15)

        float psum[4];
        #pragma unroll
        for (int r = 0; r < 4; ++r) {
            float xrr = __shfl(xsq, kch * 4 + r);
            float s = 0.f;
            #pragma unroll
            for (int f = 0; f < 8; ++f) {
                float d2 = xrr - 2.0f * acc[f][r] + cs[f];
                float qv = __builtin_amdgcn_rcpf(1.0f + d2);  // ALPHA=1 -> exp==1
                acc[f][r] = qv;
                s += qv;
            }
            s += __shfl_xor(s, 1);
            s += __shfl_xor(s, 2);
            s += __shfl_xor(s, 4);
            s += __shfl_xor(s, 8);
            psum[r] = s;   // sum over this wave's 128 cols, row kch*4+r
        }

        // ---- pairwise handshake (no block barrier, no vmcnt drain) ----
        if (c15 == 0) {
            #pragma unroll
            for (int r = 0; r < 4; ++r)
                ls_sum[t][ch][rg][kch * 4 + r] = psum[r];
        }
        asm volatile("s_waitcnt lgkmcnt(0)" ::: "memory");  // sums visible
        if (lane == 0)
            __atomic_store_n(&ls_flag[ch][rg], t + 1, __ATOMIC_RELAXED);

        volatile int* pf = (volatile int*)&ls_flag[ch ^ 1][rg];
        while (*pf <= t) { __builtin_amdgcn_s_sleep(1); }
        asm volatile("" ::: "memory");   // no hoisting of sum reads above spin

        const int row0t = trow + rg * 16;
        #pragma unroll
        for (int r = 0; r < 4; ++r) {
            float other = ls_sum[t][ch ^ 1][rg][kch * 4 + r];
            float inv = __builtin_amdgcn_rcpf(psum[r] + other);
            const size_t orow = (size_t)(row0t + kch * 4 + r) * KCL;
            #pragma unroll
            for (int f = 0; f < 8; ++f) {
                __builtin_nontemporal_store(acc[f][r] * inv,
                                            &out[orow + ch * 128 + f * 16 + c15]);
            }
        }
    }
}

extern "C" void kernel_launch(void* const* d_in, const int* in_sizes, int n_in,
                              void* d_out, int out_size, void* d_ws, size_t ws_size,
                              hipStream_t stream) {
    const float* x        = (const float*)d_in[0];
    const float* clusters = (const float*)d_in[1];
    float* out = (float*)d_out;

    // ws layout: [0, 128KB) clusters as bf16 ; [128KB, +1KB) c_sq f32
    unsigned short* cb  = (unsigned short*)d_ws;
    float*          csq = (float*)((char*)d_ws + (size_t)KCL * DDIM * sizeof(unsigned short));

    prep_kernel<<<KCL, 64, 0, stream>>>(clusters, cb, csq);
    fused_kernel<<<GRID, 512, 0, stream>>>(x, cb, csq, out);
}